// Round 18
// baseline (112.922 us; speedup 1.0000x reference)
//
#include <hip/hip_runtime.h>

typedef unsigned short u16;
typedef unsigned int u32;
typedef __bf16 bf16x8 __attribute__((ext_vector_type(8)));
typedef float f32x4 __attribute__((ext_vector_type(4)));

#define L2E 1.44269504088896340736f

static __device__ __forceinline__ u16 f2bf(float f) {
  u32 u = __float_as_uint(f);
  u32 r = (u + 0x7fffu + ((u >> 16) & 1u)) >> 16;
  return (u16)r;
}
static __device__ __forceinline__ float bf2f(u32 bits) {
  return __uint_as_float(bits << 16);
}
static __device__ __forceinline__ u32 trunc_bf(float f) {
  return __float_as_uint(f) >> 16;  // exact when f is a widened bf16 value
}
static __device__ __forceinline__ bf16x8 cvt8(f32x4 a, f32x4 b) {
  bf16x8 r;
  r[0] = (__bf16)a[0]; r[1] = (__bf16)a[1]; r[2] = (__bf16)a[2]; r[3] = (__bf16)a[3];
  r[4] = (__bf16)b[0]; r[5] = (__bf16)b[1]; r[6] = (__bf16)b[2]; r[7] = (__bf16)b[3];
  return r;
}

// ---------------- merged: wqT transpose (blocks 0-63) + wkv cvt (blocks 64-319) ----------------
__global__ __launch_bounds__(256) void prep_w(const float* __restrict__ w_qkv,
                                              u16* __restrict__ wqT,
                                              u16* __restrict__ wkvb) {
  __shared__ u16 tile[64][65];
  int bid = blockIdx.x;
  int t = threadIdx.x;
  if (bid < 64) {
    int c0 = (bid & 7) * 64, s0 = (bid >> 3) * 64;
    int r = t >> 4, cc = (t & 15) * 4;
#pragma unroll
    for (int i = 0; i < 4; ++i) {
      int row = r + i * 16;
      float4 v = *(const float4*)(w_qkv + (size_t)(c0 + row) * 512 + s0 + cc);
      tile[row][cc] = f2bf(v.x); tile[row][cc + 1] = f2bf(v.y);
      tile[row][cc + 2] = f2bf(v.z); tile[row][cc + 3] = f2bf(v.w);
    }
    __syncthreads();
#pragma unroll
    for (int i = 0; i < 4; ++i) {
      int srow = r + i * 16;
      union { u16 h[4]; uint2 u; } pk;
#pragma unroll
      for (int j = 0; j < 4; ++j) pk.h[j] = tile[cc + j][srow];
      *(uint2*)(wqT + (size_t)(s0 + srow) * 512 + c0 + cc) = pk.u;
    }
  } else {
    int i = ((bid - 64) * 256 + t) * 8;  // n = 524288
    const float* src = w_qkv + 262144;
    float4 a = *(const float4*)(src + i);
    float4 b = *(const float4*)(src + i + 4);
    union { u16 h[8]; uint4 v; } o;
    o.h[0] = f2bf(a.x); o.h[1] = f2bf(a.y); o.h[2] = f2bf(a.z); o.h[3] = f2bf(a.w);
    o.h[4] = f2bf(b.x); o.h[5] = f2bf(b.y); o.h[6] = f2bf(b.z); o.h[7] = f2bf(b.w);
    *(uint4*)(wkvb + i) = o.v;
  }
}

// ---- GEMM: BM=128, BN=128, BK=64, 4 waves, COMPACTED grid ----
// MODE 0: A = x (f32, staged raw + cvt at frag read), kv epilogue -> head-major kvh
// MODE 1: A = MT (bf16), plain bf16 store, ldc=512 (G build)
// MODE 2: A = x (f32), out epilogue (+bias, f32; B per batch); filler blocks bias-fill
template <int MODE>
__global__ __launch_bounds__(256, 4) void gemm128(const void* __restrict__ Ap,
                                                  const u16* __restrict__ Bm,
                                                  u16* __restrict__ outb,
                                                  float* __restrict__ outf,
                                                  const float* __restrict__ bias,
                                                  const int* __restrict__ lengths) {
  constexpr bool AF32 = (MODE != 1);
  __shared__ __align__(16) char smemA[AF32 ? 32768 : 16384];
  __shared__ u16 lB[8192];   // 128x64 bf16

  const int t = threadIdx.x;
  const int w = t >> 6, lane = t & 63, lm = lane & 15, lg = lane >> 4;
  const int wr = w >> 1, wc = w & 1;  // 2 (M) x 2 (N)
  const int col0 = blockIdx.y * 128;

  int row0, L = 0, myb = -1;
  if constexpr (MODE == 1) {
    row0 = blockIdx.x * 128;
  } else {
    const int pid = blockIdx.x;
    int na[8], pref = 0, panel = 0;
#pragma unroll
    for (int b = 0; b < 8; ++b) {
      int Lb = lengths[b];
      na[b] = (Lb + 127) >> 7;
      if (myb < 0 && pid < pref + na[b]) { myb = b; panel = pid - pref; L = Lb; }
      pref += na[b];
    }
    if (myb < 0) {
      if constexpr (MODE == 0) return;
      // MODE 2 filler: fully-masked panel -> bias fill
      int pid2 = pid - pref, pm = 0;
#pragma unroll
      for (int b = 0; b < 8; ++b) {
        int mb = 32 - na[b];
        if (myb < 0 && pid2 < pm + mb) { myb = b; panel = na[b] + pid2 - pm; }
        pm += mb;
      }
      row0 = myb * 4096 + panel * 128;
      for (int i = t; i < 4096; i += 256) {  // 128 rows x 32 f32x4
        int r = i >> 5, c = (i & 31) * 4;
        *(f32x4*)(outf + (size_t)(row0 + r) * 512 + col0 + c) =
            *(const f32x4*)(bias + col0 + c);
      }
      return;
    }
    row0 = myb * 4096 + panel * 128;
  }

  const float* Af = (const float*)Ap + (size_t)row0 * 512;
  const u16* Ab = (const u16*)Ap + (size_t)row0 * 512;
  const u16* Bbase = Bm + (size_t)col0 * 512;
  if constexpr (MODE == 2) Bbase += (size_t)myb * 262144;

  // A staging geometry
  size_t aoff[AF32 ? 8 : 4];
  if constexpr (AF32) {
    // 2048 16B-granules: granule g holds source slot (g&15)^(row&15), row = g>>4
#pragma unroll
    for (int i = 0; i < 8; ++i) {
      int g = i * 256 + t, r = g >> 4, s = (g & 15) ^ (r & 15);
      aoff[i] = (size_t)r * 512 + s * 4;
    }
  } else {
#pragma unroll
    for (int i = 0; i < 4; ++i) {
      int c = i * 256 + t, r = c >> 3, s = (c & 7) ^ (r & 7);
      aoff[i] = (size_t)r * 512 + s * 8;
    }
  }
  // B staging geometry (16B granules, XOR-swizzled source, linear LDS dest)
  size_t boff[4];
#pragma unroll
  for (int i = 0; i < 4; ++i) {
    int c = i * 256 + t, r = c >> 3, s = (c & 7) ^ (r & 7);
    boff[i] = (size_t)r * 512 + s * 8;
  }

  const int swz0 = (lg ^ (lm & 7)) * 8;
  const int swz1 = ((4 + lg) ^ (lm & 7)) * 8;

  f32x4 acc[4][4] = {};

  for (int kt = 0; kt < 8; ++kt) {
    if constexpr (AF32) {
      const float* sa = Af + kt * 64;
#pragma unroll
      for (int i = 0; i < 8; ++i)
        __builtin_amdgcn_global_load_lds(
            (const __attribute__((address_space(1))) void*)(sa + aoff[i]),
            (__attribute__((address_space(3))) void*)((float*)smemA + (i * 256 + w * 64) * 4),
            16, 0, 0);
    } else {
      const u16* sa = Ab + kt * 64;
#pragma unroll
      for (int i = 0; i < 4; ++i)
        __builtin_amdgcn_global_load_lds(
            (const __attribute__((address_space(1))) void*)(sa + aoff[i]),
            (__attribute__((address_space(3))) void*)((u16*)smemA + (i * 256 + w * 64) * 8),
            16, 0, 0);
    }
    const u16* sb = Bbase + kt * 64;
#pragma unroll
    for (int i = 0; i < 4; ++i)
      __builtin_amdgcn_global_load_lds(
          (const __attribute__((address_space(1))) void*)(sb + boff[i]),
          (__attribute__((address_space(3))) void*)(&lB[(i * 256 + w * 64) * 8]),
          16, 0, 0);
    __syncthreads();  // drains vmcnt(0): tile resident

    const u16* lb = &lB[(wc * 64 + lm) * 64];
    bf16x8 bfr[2][4];
#pragma unroll
    for (int nf = 0; nf < 4; ++nf) {
      bfr[0][nf] = *(const bf16x8*)(lb + nf * 1024 + swz0);
      bfr[1][nf] = *(const bf16x8*)(lb + nf * 1024 + swz1);
    }
#pragma unroll
    for (int mf = 0; mf < 4; ++mf) {
      bf16x8 af0, af1;
      if constexpr (AF32) {
        int row = wr * 64 + mf * 16 + lm, rx = row & 15;
        const float* base = (const float*)smemA;
        f32x4 a0 = *(const f32x4*)(base + (row * 16 + ((lg * 2) ^ rx)) * 4);
        f32x4 a1 = *(const f32x4*)(base + (row * 16 + ((lg * 2 + 1) ^ rx)) * 4);
        f32x4 a2 = *(const f32x4*)(base + (row * 16 + ((8 + lg * 2) ^ rx)) * 4);
        f32x4 a3 = *(const f32x4*)(base + (row * 16 + ((9 + lg * 2) ^ rx)) * 4);
        af0 = cvt8(a0, a1);
        af1 = cvt8(a2, a3);
      } else {
        const u16* la = (const u16*)smemA + (wr * 64 + lm) * 64;
        af0 = *(const bf16x8*)(la + mf * 1024 + swz0);
        af1 = *(const bf16x8*)(la + mf * 1024 + swz1);
      }
      __builtin_amdgcn_s_setprio(1);
#pragma unroll
      for (int nf = 0; nf < 4; ++nf) {
        acc[mf][nf] = __builtin_amdgcn_mfma_f32_16x16x32_bf16(
            bfr[0][nf], af0, acc[mf][nf], 0, 0, 0);
        acc[mf][nf] = __builtin_amdgcn_mfma_f32_16x16x32_bf16(
            bfr[1][nf], af1, acc[mf][nf], 0, 0, 0);
      }
      __builtin_amdgcn_s_setprio(0);
    }
    __syncthreads();  // all ds_reads done before next-tile overwrite
  }

  // lane holds C[row0 + wr*64 + mf*16 + lm][col0 + wc*64 + nf*16 + lg*4 + r]
  if constexpr (MODE == 0) {
    const int cls = col0 >> 9;  // 0=k, 1=v (uniform per block)
#pragma unroll
    for (int mf = 0; mf < 4; ++mf) {
      int grow = row0 + wr * 64 + mf * 16 + lm;
      int n = grow & 4095, bb = grow >> 12;
      bool msk = (n >= L);
#pragma unroll
      for (int nf = 0; nf < 4; ++nf) {
        int c = col0 + wc * 64 + nf * 16 + lg * 4;
        int h = (c >> 6) & 7;
        int off = (cls == 0) ? (c & 63) : (64 + (c & 63));
        f32x4 v = acc[mf][nf];
        if (msk) {
          float mv = (cls == 0) ? -1e15f : 0.f;
          v[0] = mv; v[1] = mv; v[2] = mv; v[3] = mv;
        }
        union { u16 h4[4]; uint2 u; } pk;
        pk.h4[0] = f2bf(v[0]); pk.h4[1] = f2bf(v[1]);
        pk.h4[2] = f2bf(v[2]); pk.h4[3] = f2bf(v[3]);
        *(uint2*)(outb + ((size_t)((bb * 8 + h) * 4096 + n)) * 128 + off) = pk.u;
      }
    }
  } else if constexpr (MODE == 1) {
#pragma unroll
    for (int mf = 0; mf < 4; ++mf) {
      int grow = row0 + wr * 64 + mf * 16 + lm;
      u16* rp = outb + (size_t)grow * 512 + col0 + wc * 64 + lg * 4;
#pragma unroll
      for (int nf = 0; nf < 4; ++nf) {
        f32x4 v = acc[mf][nf];
        union { u16 h4[4]; uint2 u; } pk;
        pk.h4[0] = f2bf(v[0]); pk.h4[1] = f2bf(v[1]);
        pk.h4[2] = f2bf(v[2]); pk.h4[3] = f2bf(v[3]);
        *(uint2*)(rp + nf * 16) = pk.u;
      }
    }
  } else {
    f32x4 b4[4];
#pragma unroll
    for (int nf = 0; nf < 4; ++nf)
      b4[nf] = *(const f32x4*)(bias + col0 + wc * 64 + nf * 16 + lg * 4);
#pragma unroll
    for (int mf = 0; mf < 4; ++mf) {
      int grow = row0 + wr * 64 + mf * 16 + lm;
      bool msk = ((grow & 4095) >= L);
      float* rp = outf + (size_t)grow * 512 + col0 + wc * 64 + lg * 4;
#pragma unroll
      for (int nf = 0; nf < 4; ++nf) {
        f32x4 v = msk ? b4[nf] : (acc[mf][nf] + b4[nf]);
        *(f32x4*)(rp + nf * 16) = v;
      }
    }
  }
}

// ---------------- ctx: 4 waves/block, wave = 128 rows (4 groups), LDS tree-combine ----------------
struct CtxGrp {
  bf16x8 praw[2][2], vraw[2][2];
};

static __device__ __forceinline__ void ctx_load(const u16* __restrict__ base, int g,
                                                int lm, int lg, CtxGrp& X) {
  const u16* rp = base + (size_t)(g * 32 + lm) * 128 + lg * 8;
#pragma unroll
  for (int mt = 0; mt < 2; ++mt)
#pragma unroll
    for (int dh = 0; dh < 2; ++dh) {
      const u16* p = rp + mt * 2048 + dh * 32;
      X.praw[mt][dh] = *(const bf16x8*)(p);
      X.vraw[mt][dh] = *(const bf16x8*)(p + 64);
    }
}

static __device__ __forceinline__ void ctx_compute(const CtxGrp& X, bf16x8 I1, bf16x8 I2,
                                                   f32x4 acc[4][4], float sacc[4]) {
  const f32x4 zero = {0.f, 0.f, 0.f, 0.f};
  bf16x8 pf[2][2];
#pragma unroll
  for (int mt = 0; mt < 2; ++mt)
#pragma unroll
    for (int dh = 0; dh < 2; ++dh) {
      union { bf16x8 v; u32 w4[4]; } in;
      in.v = X.praw[mt][dh];
      union { u16 h[8]; bf16x8 v; } o;
#pragma unroll
      for (int i = 0; i < 4; ++i) {
        float a = bf2f(in.w4[i] & 0xffffu) * L2E;
        float bq = bf2f(in.w4[i] >> 16) * L2E;
        o.h[2 * i] = f2bf(exp2f(a));
        o.h[2 * i + 1] = f2bf(exp2f(bq));
      }
      pf[mt][dh] = o.v;
    }

  f32x4 tP[2][4], tV[2][4];
#pragma unroll
  for (int mt = 0; mt < 2; ++mt)
#pragma unroll
    for (int dh = 0; dh < 2; ++dh) {
      tP[mt][dh * 2] = __builtin_amdgcn_mfma_f32_16x16x32_bf16(pf[mt][dh], I1, zero, 0, 0, 0);
      tP[mt][dh * 2 + 1] = __builtin_amdgcn_mfma_f32_16x16x32_bf16(pf[mt][dh], I2, zero, 0, 0, 0);
      tV[mt][dh * 2] = __builtin_amdgcn_mfma_f32_16x16x32_bf16(X.vraw[mt][dh], I1, zero, 0, 0, 0);
      tV[mt][dh * 2 + 1] = __builtin_amdgcn_mfma_f32_16x16x32_bf16(X.vraw[mt][dh], I2, zero, 0, 0, 0);
    }

#pragma unroll
  for (int dt = 0; dt < 4; ++dt)
#pragma unroll
    for (int mt = 0; mt < 2; ++mt)
      sacc[dt] += tP[mt][dt][0] + tP[mt][dt][1] + tP[mt][dt][2] + tP[mt][dt][3];

  bf16x8 A2[4], B2[4];
#pragma unroll
  for (int dt = 0; dt < 4; ++dt) {
    union { u32 w4[4]; bf16x8 v; } a, bb2;
#pragma unroll
    for (int mt = 0; mt < 2; ++mt) {
      a.w4[mt * 2] = trunc_bf(tP[mt][dt][0]) | (trunc_bf(tP[mt][dt][1]) << 16);
      a.w4[mt * 2 + 1] = trunc_bf(tP[mt][dt][2]) | (trunc_bf(tP[mt][dt][3]) << 16);
      bb2.w4[mt * 2] = trunc_bf(tV[mt][dt][0]) | (trunc_bf(tV[mt][dt][1]) << 16);
      bb2.w4[mt * 2 + 1] = trunc_bf(tV[mt][dt][2]) | (trunc_bf(tV[mt][dt][3]) << 16);
    }
    A2[dt] = a.v; B2[dt] = bb2.v;
  }

#pragma unroll
  for (int dt = 0; dt < 4; ++dt)
#pragma unroll
    for (int et = 0; et < 4; ++et)
      acc[dt][et] = __builtin_amdgcn_mfma_f32_16x16x32_bf16(A2[dt], B2[et], acc[dt][et], 0, 0, 0);
}

__global__ __launch_bounds__(256) void ctx_gemm(const u16* __restrict__ kvh,
                                                float* __restrict__ ctxp,
                                                float* __restrict__ csum,
                                                const int* __restrict__ lengths) {
  int chunk = blockIdx.x;  // 0..7 (512 rows each)
  int bh = blockIdx.y;     // 0..63
  int b = bh >> 3;
  int L = lengths[b];
  int rows = L - chunk * 512;
  if (rows <= 0) return;

  int t = threadIdx.x;
  int w = t >> 6, lane = t & 63, lm = lane & 15, lg = lane >> 4;

  int wrows = rows - w * 128;
  int ngw = (wrows <= 0) ? 0 : (wrows >= 128 ? 4 : ((wrows + 31) >> 5));

  __shared__ float red[4][4096];
  __shared__ float redc[4][64];

  bf16x8 I1, I2;
  {
    union { u16 h[8]; bf16x8 v; } u1, u2;
#pragma unroll
    for (int j = 0; j < 8; ++j) {
      u1.h[j] = (lg * 8 + j == lm) ? 0x3F80 : 0;
      u2.h[j] = (lg * 8 + j == lm + 16) ? 0x3F80 : 0;
    }
    I1 = u1.v; I2 = u2.v;
  }

  f32x4 acc[4][4] = {};
  float sacc[4] = {};

  const u16* base = kvh + ((size_t)bh * 4096 + (size_t)chunk * 512 + (size_t)w * 128) * 128;

  for (int g = 0; g < ngw; ++g) {
    CtxGrp X;
    ctx_load(base, g, lm, lg, X);
    ctx_compute(X, I1, I2, acc, sacc);
  }

#pragma unroll
  for (int dt = 0; dt < 4; ++dt)
#pragma unroll
    for (int et = 0; et < 4; ++et)
#pragma unroll
      for (int r = 0; r < 4; ++r)
        red[w][(dt * 16 + lg * 4 + r) * 64 + et * 16 + lm] = acc[dt][et][r];
#pragma unroll
  for (int dt = 0; dt < 4; ++dt) {
    float s = sacc[dt];
    s += __shfl_xor(s, 16);
    s += __shfl_xor(s, 32);
    if (lg == 0) redc[w][dt * 16 + lm] = s;
  }
  __syncthreads();

  float* outp = ctxp + ((size_t)bh * 8 + chunk) * 4096;
#pragma unroll
  for (int j = 0; j < 4; ++j) {
    int i = t * 4 + j * 1024;
    f32x4 v = *(const f32x4*)&red[0][i];
    v += *(const f32x4*)&red[1][i];
    v += *(const f32x4*)&red[2][i];
    v += *(const f32x4*)&red[3][i];
    *(f32x4*)(outp + i) = v;
  }
  if (t < 64)
    csum[((size_t)bh * 8 + chunk) * 64 + t] =
        redc[0][t] + redc[1][t] + redc[2][t] + redc[3][t];
}

// ---------------- parallel chunk reduction: ctxr[bh][i] = sum_ch ctxp[bh][ch][i] ----------------
__global__ __launch_bounds__(256) void reduce_ctx(const float* __restrict__ ctxp,
                                                  float* __restrict__ ctxr,
                                                  const int* __restrict__ lengths) {
  int blk = blockIdx.x;          // 0..255
  int bh = blk >> 2, s = blk & 3;
  int nch = (lengths[bh >> 3] + 511) >> 9;  // 1..8
  int i = s * 1024 + threadIdx.x * 4;
  const float* p = ctxp + (size_t)bh * 8 * 4096 + i;
  f32x4 acc = {0.f, 0.f, 0.f, 0.f};
  for (int ch = 0; ch < nch; ++ch) acc += *(const f32x4*)(p + (size_t)ch * 4096);
  *(f32x4*)(ctxr + (size_t)bh * 4096 + i) = acc;
}

// ---------------- MT[b][dd][64h+d] = SCALE * sum_e (ctx[d,e]/den[d]) * w_out[dd][64h+e] ----------------
__global__ __launch_bounds__(256) void m_gemm(const float* __restrict__ ctxr,
                                              const float* __restrict__ csum,
                                              const float* __restrict__ w_out,
                                              u16* __restrict__ MT,
                                              const int* __restrict__ lengths) {
  int bh = blockIdx.x;
  int grp = blockIdx.y;
  int b = bh >> 3, h = bh & 7;
  int nch = (lengths[b] + 511) >> 9;
  int dd0 = grp * 128;
  int t = threadIdx.x;
  __shared__ short sctx[64 * 64];
  __shared__ short sw[128 * 64];
  {
    const float* cp = ctxr + (size_t)bh * 4096;
    int i0 = t * 16;
    int d = t >> 2;
    float den = 0.f;
    for (int ch = 0; ch < nch; ++ch) den += csum[((size_t)bh * 8 + ch) * 64 + d];
    float rin = 1.0f / den;
#pragma unroll
    for (int j = 0; j < 16; j += 4) {
      float4 v = *(const float4*)(cp + i0 + j);
      sctx[i0 + j] = (short)f2bf(v.x * rin);
      sctx[i0 + j + 1] = (short)f2bf(v.y * rin);
      sctx[i0 + j + 2] = (short)f2bf(v.z * rin);
      sctx[i0 + j + 3] = (short)f2bf(v.w * rin);
    }
  }
  {
#pragma unroll
    for (int j = 0; j < 32; j += 4) {
      int idx = t * 32 + j;
      int row = idx >> 6, col = idx & 63;
      float4 v = *(const float4*)(w_out + (size_t)(dd0 + row) * 512 + h * 64 + col);
      sw[idx] = (short)f2bf(v.x); sw[idx + 1] = (short)f2bf(v.y);
      sw[idx + 2] = (short)f2bf(v.z); sw[idx + 3] = (short)f2bf(v.w);
    }
  }
  __syncthreads();

  int lane = t & 63, w = t >> 6;
  int lm = lane & 15, lk = (lane >> 4) * 8;
  f32x4 acc[2][4] = {};
#pragma unroll
  for (int kk = 0; kk < 2; ++kk) {
    bf16x8 af[2], bfr[4];
#pragma unroll
    for (int mb = 0; mb < 2; ++mb)
      af[mb] = *(const bf16x8*)(sw + (w * 32 + mb * 16 + lm) * 64 + kk * 32 + lk);
#pragma unroll
    for (int nb = 0; nb < 4; ++nb)
      bfr[nb] = *(const bf16x8*)(sctx + (nb * 16 + lm) * 64 + kk * 32 + lk);
#pragma unroll
    for (int mb = 0; mb < 2; ++mb)
#pragma unroll
      for (int nb = 0; nb < 4; ++nb)
        acc[mb][nb] = __builtin_amdgcn_mfma_f32_16x16x32_bf16(af[mb], bfr[nb], acc[mb][nb], 0, 0, 0);
  }
  u16* outp = MT + (size_t)b * 512 * 512;
#pragma unroll
  for (int mb = 0; mb < 2; ++mb)
#pragma unroll
    for (int r = 0; r < 4; ++r) {
      int dd = dd0 + w * 32 + mb * 16 + (lane >> 4) * 4 + r;
#pragma unroll
      for (int nb = 0; nb < 4; ++nb) {
        int c = h * 64 + nb * 16 + lm;
        outp[dd * 512 + c] = f2bf(acc[mb][nb][r] * 0.125f);  // SCALE folded here
      }
    }
}

extern "C" void kernel_launch(void* const* d_in, const int* in_sizes, int n_in,
                              void* d_out, int out_size, void* d_ws, size_t ws_size,
                              hipStream_t stream) {
  const float* x = (const float*)d_in[0];
  const float* w_qkv = (const float*)d_in[1];
  const float* w_out = (const float*)d_in[2];
  const float* b_out = (const float*)d_in[3];
  const int* lengths = (const int*)d_in[4];
  float* out = (float*)d_out;
  char* ws = (char*)d_ws;

  u16* kvh    = (u16*)(ws);                     // 67,108,864 B
  u16* wkvb   = (u16*)(ws + 67108864);          // 1,048,576 B
  u16* wqT    = (u16*)(ws + 68157440);          // 524,288 B
  float* ctxp = (float*)(ws + 68681728);        // 8,388,608 B
  float* csum = (float*)(ws + 77070336);        // 131,072 B
  float* ctxr = (float*)(ws + 77201408);        // 1,048,576 B
  u16* MT     = (u16*)(ws + 78249984);          // 4,194,304 B
  u16* G      = (u16*)(ws + 82444288);          // 4,194,304 B

  prep_w<<<320, 256, 0, stream>>>(w_qkv, wqT, wkvb);
  gemm128<0><<<dim3(256, 8), 256, 0, stream>>>(x, wkvb, kvh, nullptr, nullptr, lengths);
  ctx_gemm<<<dim3(8, 64), 256, 0, stream>>>(kvh, ctxp, csum, lengths);
  reduce_ctx<<<256, 256, 0, stream>>>(ctxp, ctxr, lengths);
  m_gemm<<<dim3(64, 4), 256, 0, stream>>>(ctxr, csum, w_out, MT, lengths);
  gemm128<1><<<dim3(32, 4), 256, 0, stream>>>(MT, wqT, G, nullptr, nullptr, nullptr);
  gemm128<2><<<dim3(256, 4), 256, 0, stream>>>(x, G, nullptr, out, b_out, lengths);
}

// Round 19
// 107.224 us; speedup vs baseline: 1.0531x; 1.0531x over previous
//
#include <hip/hip_runtime.h>

typedef unsigned short u16;
typedef unsigned int u32;
typedef __bf16 bf16x8 __attribute__((ext_vector_type(8)));
typedef float f32x4 __attribute__((ext_vector_type(4)));

#define L2E 1.44269504088896340736f

static __device__ __forceinline__ u16 f2bf(float f) {
  u32 u = __float_as_uint(f);
  u32 r = (u + 0x7fffu + ((u >> 16) & 1u)) >> 16;
  return (u16)r;
}
static __device__ __forceinline__ float bf2f(u32 bits) {
  return __uint_as_float(bits << 16);
}
static __device__ __forceinline__ u32 trunc_bf(float f) {
  return __float_as_uint(f) >> 16;  // exact when f is a widened bf16 value
}

// ---------------- x -> bf16 with row skip ----------------
__global__ __launch_bounds__(256) void cvt_x(const float* __restrict__ src,
                                             u16* __restrict__ dst,
                                             const int* __restrict__ lengths) {
  int i = (blockIdx.x * 256 + threadIdx.x) * 8;  // n = 16777216
  int row = i >> 9;
  if ((row & 4095) >= lengths[row >> 12]) return;
  float4 a = *(const float4*)(src + i);
  float4 b = *(const float4*)(src + i + 4);
  union { u16 h[8]; uint4 v; } o;
  o.h[0] = f2bf(a.x); o.h[1] = f2bf(a.y); o.h[2] = f2bf(a.z); o.h[3] = f2bf(a.w);
  o.h[4] = f2bf(b.x); o.h[5] = f2bf(b.y); o.h[6] = f2bf(b.z); o.h[7] = f2bf(b.w);
  *(uint4*)(dst + i) = o.v;
}

// ---------------- merged: wqT transpose (blocks 0-63) + wkv cvt (blocks 64-319) ----------------
__global__ __launch_bounds__(256) void prep_w(const float* __restrict__ w_qkv,
                                              u16* __restrict__ wqT,
                                              u16* __restrict__ wkvb) {
  __shared__ u16 tile[64][65];
  int bid = blockIdx.x;
  int t = threadIdx.x;
  if (bid < 64) {
    int c0 = (bid & 7) * 64, s0 = (bid >> 3) * 64;
    int r = t >> 4, cc = (t & 15) * 4;
#pragma unroll
    for (int i = 0; i < 4; ++i) {
      int row = r + i * 16;
      float4 v = *(const float4*)(w_qkv + (size_t)(c0 + row) * 512 + s0 + cc);
      tile[row][cc] = f2bf(v.x); tile[row][cc + 1] = f2bf(v.y);
      tile[row][cc + 2] = f2bf(v.z); tile[row][cc + 3] = f2bf(v.w);
    }
    __syncthreads();
#pragma unroll
    for (int i = 0; i < 4; ++i) {
      int srow = r + i * 16;
      union { u16 h[4]; uint2 u; } pk;
#pragma unroll
      for (int j = 0; j < 4; ++j) pk.h[j] = tile[cc + j][srow];
      *(uint2*)(wqT + (size_t)(s0 + srow) * 512 + c0 + cc) = pk.u;
    }
  } else {
    int i = ((bid - 64) * 256 + t) * 8;  // n = 524288
    const float* src = w_qkv + 262144;
    float4 a = *(const float4*)(src + i);
    float4 b = *(const float4*)(src + i + 4);
    union { u16 h[8]; uint4 v; } o;
    o.h[0] = f2bf(a.x); o.h[1] = f2bf(a.y); o.h[2] = f2bf(a.z); o.h[3] = f2bf(a.w);
    o.h[4] = f2bf(b.x); o.h[5] = f2bf(b.y); o.h[6] = f2bf(b.z); o.h[7] = f2bf(b.w);
    *(uint4*)(wkvb + i) = o.v;
  }
}

// ---- GEMM: BM=128, BN=128, BK=64, 4 waves, 32KiB LDS, launch_bounds(256,4), COMPACTED grid ----
// C[r,c] = sum_k A[r,k]*B[c,k], lda=ldb=512, K=512.
// MODE 0: kv epilogue -> head-major kvh[(b*8+h)][n][128] (k cols 0-63, v cols 64-127)
// MODE 1: plain bf16 store, ldc=512 (G build), no length logic
// MODE 2: out epilogue (+bias, f32, ldc=512; B offset per batch); filler blocks bias-fill
template <int MODE>
__global__ __launch_bounds__(256, 4) void gemm128(const u16* __restrict__ A,
                                                  const u16* __restrict__ Bm,
                                                  u16* __restrict__ outb,
                                                  float* __restrict__ outf,
                                                  const float* __restrict__ bias,
                                                  const int* __restrict__ lengths) {
  __shared__ u16 lA[8192];   // 128x64
  __shared__ u16 lB[8192];   // 128x64

  const int t = threadIdx.x;
  const int w = t >> 6, lane = t & 63, lm = lane & 15, lg = lane >> 4;
  const int wr = w >> 1, wc = w & 1;  // 2 (M) x 2 (N)
  const int col0 = blockIdx.y * 128;

  int row0, L = 0, myb = -1;
  if constexpr (MODE == 1) {
    row0 = blockIdx.x * 128;
  } else {
    const int pid = blockIdx.x;
    int na[8], pref = 0, panel = 0;
#pragma unroll
    for (int b = 0; b < 8; ++b) {
      int Lb = lengths[b];
      na[b] = (Lb + 127) >> 7;
      if (myb < 0 && pid < pref + na[b]) { myb = b; panel = pid - pref; L = Lb; }
      pref += na[b];
    }
    if (myb < 0) {
      if constexpr (MODE == 0) return;
      // MODE 2 filler: fully-masked panel -> bias fill
      int pid2 = pid - pref, pm = 0;
#pragma unroll
      for (int b = 0; b < 8; ++b) {
        int mb = 32 - na[b];
        if (myb < 0 && pid2 < pm + mb) { myb = b; panel = na[b] + pid2 - pm; }
        pm += mb;
      }
      row0 = myb * 4096 + panel * 128;
      for (int i = t; i < 4096; i += 256) {  // 128 rows x 32 f32x4
        int r = i >> 5, c = (i & 31) * 4;
        *(f32x4*)(outf + (size_t)(row0 + r) * 512 + col0 + c) =
            *(const f32x4*)(bias + col0 + c);
      }
      return;
    }
    row0 = myb * 4096 + panel * 128;
  }

  const u16* Abase = A + (size_t)row0 * 512;
  const u16* Bbase = Bm + (size_t)col0 * 512;
  if constexpr (MODE == 2) Bbase += (size_t)myb * 262144;

  // staging geometry (16B granules, XOR-swizzled source, linear LDS dest)
  size_t goff[4];
#pragma unroll
  for (int i = 0; i < 4; ++i) {
    int c = i * 256 + t, r = c >> 3, s = (c & 7) ^ (r & 7);
    goff[i] = (size_t)r * 512 + s * 8;
  }

  const int swz0 = (lg ^ (lm & 7)) * 8;
  const int swz1 = ((4 + lg) ^ (lm & 7)) * 8;

  f32x4 acc[4][4] = {};

  for (int kt = 0; kt < 8; ++kt) {
    const u16* sa = Abase + kt * 64;
    const u16* sb = Bbase + kt * 64;
#pragma unroll
    for (int i = 0; i < 4; ++i)
      __builtin_amdgcn_global_load_lds(
          (const __attribute__((address_space(1))) void*)(sa + goff[i]),
          (__attribute__((address_space(3))) void*)(&lA[(i * 256 + w * 64) * 8]),
          16, 0, 0);
#pragma unroll
    for (int i = 0; i < 4; ++i)
      __builtin_amdgcn_global_load_lds(
          (const __attribute__((address_space(1))) void*)(sb + goff[i]),
          (__attribute__((address_space(3))) void*)(&lB[(i * 256 + w * 64) * 8]),
          16, 0, 0);
    __syncthreads();  // drains vmcnt(0): tile resident

    const u16* la = &lA[(wr * 64 + lm) * 64];
    const u16* lb = &lB[(wc * 64 + lm) * 64];
    bf16x8 bfr[2][4];
#pragma unroll
    for (int nf = 0; nf < 4; ++nf) {
      bfr[0][nf] = *(const bf16x8*)(lb + nf * 1024 + swz0);
      bfr[1][nf] = *(const bf16x8*)(lb + nf * 1024 + swz1);
    }
#pragma unroll
    for (int mf = 0; mf < 4; ++mf) {
      bf16x8 af0 = *(const bf16x8*)(la + mf * 1024 + swz0);
      bf16x8 af1 = *(const bf16x8*)(la + mf * 1024 + swz1);
      __builtin_amdgcn_s_setprio(1);
#pragma unroll
      for (int nf = 0; nf < 4; ++nf) {
        acc[mf][nf] = __builtin_amdgcn_mfma_f32_16x16x32_bf16(
            bfr[0][nf], af0, acc[mf][nf], 0, 0, 0);
        acc[mf][nf] = __builtin_amdgcn_mfma_f32_16x16x32_bf16(
            bfr[1][nf], af1, acc[mf][nf], 0, 0, 0);
      }
      __builtin_amdgcn_s_setprio(0);
    }
    __syncthreads();  // all ds_reads done before next-tile overwrite
  }

  // lane holds C[row0 + wr*64 + mf*16 + lm][col0 + wc*64 + nf*16 + lg*4 + r]
  if constexpr (MODE == 0) {
    const int cls = col0 >> 9;  // 0=k, 1=v (uniform per block)
#pragma unroll
    for (int mf = 0; mf < 4; ++mf) {
      int grow = row0 + wr * 64 + mf * 16 + lm;
      int n = grow & 4095, bb = grow >> 12;
      bool msk = (n >= L);
#pragma unroll
      for (int nf = 0; nf < 4; ++nf) {
        int c = col0 + wc * 64 + nf * 16 + lg * 4;
        int h = (c >> 6) & 7;
        int off = (cls == 0) ? (c & 63) : (64 + (c & 63));
        f32x4 v = acc[mf][nf];
        if (msk) {
          float mv = (cls == 0) ? -1e15f : 0.f;
          v[0] = mv; v[1] = mv; v[2] = mv; v[3] = mv;
        }
        union { u16 h4[4]; uint2 u; } pk;
        pk.h4[0] = f2bf(v[0]); pk.h4[1] = f2bf(v[1]);
        pk.h4[2] = f2bf(v[2]); pk.h4[3] = f2bf(v[3]);
        *(uint2*)(outb + ((size_t)((bb * 8 + h) * 4096 + n)) * 128 + off) = pk.u;
      }
    }
  } else if constexpr (MODE == 1) {
#pragma unroll
    for (int mf = 0; mf < 4; ++mf) {
      int grow = row0 + wr * 64 + mf * 16 + lm;
      u16* rp = outb + (size_t)grow * 512 + col0 + wc * 64 + lg * 4;
#pragma unroll
      for (int nf = 0; nf < 4; ++nf) {
        f32x4 v = acc[mf][nf];
        union { u16 h4[4]; uint2 u; } pk;
        pk.h4[0] = f2bf(v[0]); pk.h4[1] = f2bf(v[1]);
        pk.h4[2] = f2bf(v[2]); pk.h4[3] = f2bf(v[3]);
        *(uint2*)(rp + nf * 16) = pk.u;
      }
    }
  } else {
    f32x4 b4[4];
#pragma unroll
    for (int nf = 0; nf < 4; ++nf)
      b4[nf] = *(const f32x4*)(bias + col0 + wc * 64 + nf * 16 + lg * 4);
#pragma unroll
    for (int mf = 0; mf < 4; ++mf) {
      int grow = row0 + wr * 64 + mf * 16 + lm;
      bool msk = ((grow & 4095) >= L);
      float* rp = outf + (size_t)grow * 512 + col0 + wc * 64 + lg * 4;
#pragma unroll
      for (int nf = 0; nf < 4; ++nf) {
        f32x4 v = msk ? b4[nf] : (acc[mf][nf] + b4[nf]);
        *(f32x4*)(rp + nf * 16) = v;
      }
    }
  }
}

// ---------------- ctx: 4 waves/block, wave = 128 rows (4 groups), LDS tree-combine ----------------
// ctx[d,e] = sum_n P[n,d]*V[n,e],  P = exp(k);  csum[d] = sum_n P[n,d]
struct CtxGrp {
  bf16x8 praw[2][2], vraw[2][2];
};

static __device__ __forceinline__ void ctx_load(const u16* __restrict__ base, int g,
                                                int lm, int lg, CtxGrp& X) {
  const u16* rp = base + (size_t)(g * 32 + lm) * 128 + lg * 8;
#pragma unroll
  for (int mt = 0; mt < 2; ++mt)
#pragma unroll
    for (int dh = 0; dh < 2; ++dh) {
      const u16* p = rp + mt * 2048 + dh * 32;
      X.praw[mt][dh] = *(const bf16x8*)(p);
      X.vraw[mt][dh] = *(const bf16x8*)(p + 64);
    }
}

static __device__ __forceinline__ void ctx_compute(const CtxGrp& X, bf16x8 I1, bf16x8 I2,
                                                   f32x4 acc[4][4], float sacc[4]) {
  const f32x4 zero = {0.f, 0.f, 0.f, 0.f};
  bf16x8 pf[2][2];
#pragma unroll
  for (int mt = 0; mt < 2; ++mt)
#pragma unroll
    for (int dh = 0; dh < 2; ++dh) {
      union { bf16x8 v; u32 w4[4]; } in;
      in.v = X.praw[mt][dh];
      union { u16 h[8]; bf16x8 v; } o;
#pragma unroll
      for (int i = 0; i < 4; ++i) {
        float a = bf2f(in.w4[i] & 0xffffu) * L2E;
        float bq = bf2f(in.w4[i] >> 16) * L2E;
        o.h[2 * i] = f2bf(exp2f(a));
        o.h[2 * i + 1] = f2bf(exp2f(bq));
      }
      pf[mt][dh] = o.v;
    }

  f32x4 tP[2][4], tV[2][4];
#pragma unroll
  for (int mt = 0; mt < 2; ++mt)
#pragma unroll
    for (int dh = 0; dh < 2; ++dh) {
      tP[mt][dh * 2] = __builtin_amdgcn_mfma_f32_16x16x32_bf16(pf[mt][dh], I1, zero, 0, 0, 0);
      tP[mt][dh * 2 + 1] = __builtin_amdgcn_mfma_f32_16x16x32_bf16(pf[mt][dh], I2, zero, 0, 0, 0);
      tV[mt][dh * 2] = __builtin_amdgcn_mfma_f32_16x16x32_bf16(X.vraw[mt][dh], I1, zero, 0, 0, 0);
      tV[mt][dh * 2 + 1] = __builtin_amdgcn_mfma_f32_16x16x32_bf16(X.vraw[mt][dh], I2, zero, 0, 0, 0);
    }

#pragma unroll
  for (int dt = 0; dt < 4; ++dt)
#pragma unroll
    for (int mt = 0; mt < 2; ++mt)
      sacc[dt] += tP[mt][dt][0] + tP[mt][dt][1] + tP[mt][dt][2] + tP[mt][dt][3];

  bf16x8 A2[4], B2[4];
#pragma unroll
  for (int dt = 0; dt < 4; ++dt) {
    union { u32 w4[4]; bf16x8 v; } a, bb2;
#pragma unroll
    for (int mt = 0; mt < 2; ++mt) {
      a.w4[mt * 2] = trunc_bf(tP[mt][dt][0]) | (trunc_bf(tP[mt][dt][1]) << 16);
      a.w4[mt * 2 + 1] = trunc_bf(tP[mt][dt][2]) | (trunc_bf(tP[mt][dt][3]) << 16);
      bb2.w4[mt * 2] = trunc_bf(tV[mt][dt][0]) | (trunc_bf(tV[mt][dt][1]) << 16);
      bb2.w4[mt * 2 + 1] = trunc_bf(tV[mt][dt][2]) | (trunc_bf(tV[mt][dt][3]) << 16);
    }
    A2[dt] = a.v; B2[dt] = bb2.v;
  }

#pragma unroll
  for (int dt = 0; dt < 4; ++dt)
#pragma unroll
    for (int et = 0; et < 4; ++et)
      acc[dt][et] = __builtin_amdgcn_mfma_f32_16x16x32_bf16(A2[dt], B2[et], acc[dt][et], 0, 0, 0);
}

__global__ __launch_bounds__(256) void ctx_gemm(const u16* __restrict__ kvh,
                                                float* __restrict__ ctxp,
                                                float* __restrict__ csum,
                                                const int* __restrict__ lengths) {
  int chunk = blockIdx.x;  // 0..7 (512 rows each)
  int bh = blockIdx.y;     // 0..63
  int b = bh >> 3;
  int L = lengths[b];
  int rows = L - chunk * 512;
  if (rows <= 0) return;   // uniform per block

  int t = threadIdx.x;
  int w = t >> 6, lane = t & 63, lm = lane & 15, lg = lane >> 4;

  // wave w covers rows [chunk*512 + w*128, +128): up to 4 groups of 32
  int wrows = rows - w * 128;
  int ngw = (wrows <= 0) ? 0 : (wrows >= 128 ? 4 : ((wrows + 31) >> 5));

  __shared__ float red[4][4096];
  __shared__ float redc[4][64];

  // identity B-frags: I1[nn][k] = (k==nn), I2[nn][k] = (k-16==nn); nn=lm, k=lg*8+j
  bf16x8 I1, I2;
  {
    union { u16 h[8]; bf16x8 v; } u1, u2;
#pragma unroll
    for (int j = 0; j < 8; ++j) {
      u1.h[j] = (lg * 8 + j == lm) ? 0x3F80 : 0;
      u2.h[j] = (lg * 8 + j == lm + 16) ? 0x3F80 : 0;
    }
    I1 = u1.v; I2 = u2.v;
  }

  f32x4 acc[4][4] = {};   // [dt][et]: lane holds ctx[dt*16+lg*4+r][et*16+lm]
  float sacc[4] = {};

  const u16* base = kvh + ((size_t)bh * 4096 + (size_t)chunk * 512 + (size_t)w * 128) * 128;

  for (int g = 0; g < ngw; ++g) {
    CtxGrp X;
    ctx_load(base, g, lm, lg, X);
    ctx_compute(X, I1, I2, acc, sacc);
  }

  // per-wave results to LDS (own slice, no atomics)
#pragma unroll
  for (int dt = 0; dt < 4; ++dt)
#pragma unroll
    for (int et = 0; et < 4; ++et)
#pragma unroll
      for (int r = 0; r < 4; ++r)
        red[w][(dt * 16 + lg * 4 + r) * 64 + et * 16 + lm] = acc[dt][et][r];
#pragma unroll
  for (int dt = 0; dt < 4; ++dt) {
    float s = sacc[dt];
    s += __shfl_xor(s, 16);
    s += __shfl_xor(s, 32);
    if (lg == 0) redc[w][dt * 16 + lm] = s;
  }
  __syncthreads();

  // cooperative 4-way combine, vectorized, conflict-free stride
  float* outp = ctxp + ((size_t)bh * 8 + chunk) * 4096;
#pragma unroll
  for (int j = 0; j < 4; ++j) {
    int i = t * 4 + j * 1024;
    f32x4 v = *(const f32x4*)&red[0][i];
    v += *(const f32x4*)&red[1][i];
    v += *(const f32x4*)&red[2][i];
    v += *(const f32x4*)&red[3][i];
    *(f32x4*)(outp + i) = v;
  }
  if (t < 64)
    csum[((size_t)bh * 8 + chunk) * 64 + t] =
        redc[0][t] + redc[1][t] + redc[2][t] + redc[3][t];
}

// ---------------- parallel chunk reduction: ctxr[bh][i] = sum_ch ctxp[bh][ch][i] ----------------
__global__ __launch_bounds__(256) void reduce_ctx(const float* __restrict__ ctxp,
                                                  float* __restrict__ ctxr,
                                                  const int* __restrict__ lengths) {
  int blk = blockIdx.x;          // 0..255
  int bh = blk >> 2, s = blk & 3;
  int nch = (lengths[bh >> 3] + 511) >> 9;  // 1..8
  int i = s * 1024 + threadIdx.x * 4;
  const float* p = ctxp + (size_t)bh * 8 * 4096 + i;
  f32x4 acc = {0.f, 0.f, 0.f, 0.f};
  for (int ch = 0; ch < nch; ++ch) acc += *(const f32x4*)(p + (size_t)ch * 4096);
  *(f32x4*)(ctxr + (size_t)bh * 4096 + i) = acc;
}

// ---------------- MT[b][dd][64h+d] = SCALE * sum_e (ctx[d,e]/den[d]) * w_out[dd][64h+e] ----------------
__global__ __launch_bounds__(256) void m_gemm(const float* __restrict__ ctxr,
                                              const float* __restrict__ csum,
                                              const float* __restrict__ w_out,
                                              u16* __restrict__ MT,
                                              const int* __restrict__ lengths) {
  int bh = blockIdx.x;
  int grp = blockIdx.y;
  int b = bh >> 3, h = bh & 7;
  int nch = (lengths[b] + 511) >> 9;
  int dd0 = grp * 128;
  int t = threadIdx.x;
  __shared__ short sctx[64 * 64];
  __shared__ short sw[128 * 64];
  {
    const float* cp = ctxr + (size_t)bh * 4096;
    int i0 = t * 16;
    int d = t >> 2;
    float den = 0.f;
    for (int ch = 0; ch < nch; ++ch) den += csum[((size_t)bh * 8 + ch) * 64 + d];
    float rin = 1.0f / den;
#pragma unroll
    for (int j = 0; j < 16; j += 4) {
      float4 v = *(const float4*)(cp + i0 + j);
      sctx[i0 + j] = (short)f2bf(v.x * rin);
      sctx[i0 + j + 1] = (short)f2bf(v.y * rin);
      sctx[i0 + j + 2] = (short)f2bf(v.z * rin);
      sctx[i0 + j + 3] = (short)f2bf(v.w * rin);
    }
  }
  {
#pragma unroll
    for (int j = 0; j < 32; j += 4) {
      int idx = t * 32 + j;
      int row = idx >> 6, col = idx & 63;
      float4 v = *(const float4*)(w_out + (size_t)(dd0 + row) * 512 + h * 64 + col);
      sw[idx] = (short)f2bf(v.x); sw[idx + 1] = (short)f2bf(v.y);
      sw[idx + 2] = (short)f2bf(v.z); sw[idx + 3] = (short)f2bf(v.w);
    }
  }
  __syncthreads();

  int lane = t & 63, w = t >> 6;
  int lm = lane & 15, lk = (lane >> 4) * 8;
  f32x4 acc[2][4] = {};
#pragma unroll
  for (int kk = 0; kk < 2; ++kk) {
    bf16x8 af[2], bfr[4];
#pragma unroll
    for (int mb = 0; mb < 2; ++mb)
      af[mb] = *(const bf16x8*)(sw + (w * 32 + mb * 16 + lm) * 64 + kk * 32 + lk);
#pragma unroll
    for (int nb = 0; nb < 4; ++nb)
      bfr[nb] = *(const bf16x8*)(sctx + (nb * 16 + lm) * 64 + kk * 32 + lk);
#pragma unroll
    for (int mb = 0; mb < 2; ++mb)
#pragma unroll
      for (int nb = 0; nb < 4; ++nb)
        acc[mb][nb] = __builtin_amdgcn_mfma_f32_16x16x32_bf16(af[mb], bfr[nb], acc[mb][nb], 0, 0, 0);
  }
  u16* outp = MT + (size_t)b * 512 * 512;
#pragma unroll
  for (int mb = 0; mb < 2; ++mb)
#pragma unroll
    for (int r = 0; r < 4; ++r) {
      int dd = dd0 + w * 32 + mb * 16 + (lane >> 4) * 4 + r;
#pragma unroll
      for (int nb = 0; nb < 4; ++nb) {
        int c = h * 64 + nb * 16 + lm;
        outp[dd * 512 + c] = f2bf(acc[mb][nb][r] * 0.125f);  // SCALE folded here
      }
    }
}

extern "C" void kernel_launch(void* const* d_in, const int* in_sizes, int n_in,
                              void* d_out, int out_size, void* d_ws, size_t ws_size,
                              hipStream_t stream) {
  const float* x = (const float*)d_in[0];
  const float* w_qkv = (const float*)d_in[1];
  const float* w_out = (const float*)d_in[2];
  const float* b_out = (const float*)d_in[3];
  const int* lengths = (const int*)d_in[4];
  float* out = (float*)d_out;
  char* ws = (char*)d_ws;

  u16* kvh    = (u16*)(ws);                     // 67,108,864 B
  u16* xb     = (u16*)(ws + 67108864);          // 33,554,432 B
  u16* wkvb   = (u16*)(ws + 100663296);         // 1,048,576 B
  u16* wqT    = (u16*)(ws + 101711872);         // 524,288 B
  float* ctxp = (float*)(ws + 102236160);       // 8,388,608 B
  float* csum = (float*)(ws + 110624768);       // 131,072 B
  float* ctxr = (float*)(ws + 110755840);       // 1,048,576 B
  u16* MT     = (u16*)(ws + 111804416);         // 4,194,304 B
  u16* G      = (u16*)(ws + 115998720);         // 4,194,304 B

  cvt_x<<<8192, 256, 0, stream>>>(x, xb, lengths);
  prep_w<<<320, 256, 0, stream>>>(w_qkv, wqT, wkvb);
  gemm128<0><<<dim3(256, 8), 256, 0, stream>>>(xb, wkvb, kvh, nullptr, nullptr, lengths);
  ctx_gemm<<<dim3(8, 64), 256, 0, stream>>>(kvh, ctxp, csum, lengths);
  reduce_ctx<<<256, 256, 0, stream>>>(ctxp, ctxr, lengths);
  m_gemm<<<dim3(64, 4), 256, 0, stream>>>(ctxr, csum, w_out, MT, lengths);
  gemm128<1><<<dim3(32, 4), 256, 0, stream>>>(MT, wqT, G, nullptr, nullptr, nullptr);
  gemm128<2><<<dim3(256, 4), 256, 0, stream>>>(xb, G, nullptr, out, b_out, lengths);
}